// Round 1
// baseline (683.244 us; speedup 1.0000x reference)
//
#include <hip/hip_runtime.h>

// Problem: S=2048, B=32, H=1024
// out[b*S+s] = softmax_s( sum_k tanh( pre_e[m,k] + pre_h[b,k] + bias[k] ) * v[k] )
// with m = s*B + b, pre_e = Enc(M=65536,K=1024) @ We^T, We[n][k] = W[n*2H + H + k]

#define LDT 40   // padded LDS row stride (shorts): 32 + 8 pad -> 2-way-max bank conflicts

typedef __attribute__((ext_vector_type(8))) short short8;
typedef __attribute__((ext_vector_type(4))) float floatx4;

__device__ __forceinline__ short f2b(float f) {
  union { float f; unsigned u; } c; c.f = f;
  unsigned r = c.u + 0x7fffu + ((c.u >> 16) & 1u);   // RNE to bf16
  return (short)(r >> 16);
}

__device__ __forceinline__ float fast_tanh(float x) {
  float e = __expf(2.0f * x);
  return 1.0f - 2.0f / (e + 1.0f);
}

// t[b][k] = sum_j hidden[b][j] * W[k][j] + bias[k]   (one wave per (b,k))
__global__ __launch_bounds__(256) void k_preh(
    const float* __restrict__ hidden, const float* __restrict__ W,
    const float* __restrict__ bias, float* __restrict__ tpre) {
  const int wv   = (blockIdx.x << 2) + (threadIdx.x >> 6);  // 0..32767
  const int lane = threadIdx.x & 63;
  const int b = wv & 31;
  const int k = wv >> 5;
  const float* wr = W + (size_t)k * 2048;       // Wh row k
  const float* hr = hidden + b * 1024;
  float s = 0.f;
  #pragma unroll
  for (int j = 0; j < 1024; j += 64) s += wr[j + lane] * hr[j + lane];
  #pragma unroll
  for (int off = 32; off; off >>= 1) s += __shfl_xor(s, off, 64);
  if (lane == 0) tpre[b * 1024 + k] = s + bias[k];
}

// Fused GEMM + tanh + v-dot. Tile 128x128, BK=32, 4 waves (2x2 of 64x64).
__global__ __launch_bounds__(256) void k_gemm(
    const float* __restrict__ A,      // enc: [65536][1024] fp32 (m = s*B+b)
    const float* __restrict__ W,      // [1024][2048] fp32
    const float* __restrict__ tpre,   // [32][1024]
    const float* __restrict__ vvec,   // [1024]
    float* __restrict__ scores) {     // [65536], pre-zeroed
  __shared__ short As[128 * LDT];
  __shared__ short Bs[128 * LDT];

  // XCD swizzle: blocks with equal (blockIdx%8) share an XCD (round-robin
  // heuristic). Put all 8 n-tiles of an m-panel at the same residue so the
  // 512 KB A panel is fetched once per XCD L2, not 8x from HBM.
  const int l = blockIdx.x;
  const int x = l & 7;
  const int j = l >> 3;
  const int Mbase = (x * 64 + (j >> 3)) * 128;   // 512 m-tiles
  const int Nbase = (j & 7) * 128;               // 8 n-tiles

  const int tid  = threadIdx.x;
  const int lane = tid & 63;
  const int w    = tid >> 6;
  const int wm   = w >> 1, wn = w & 1;
  const int c    = lane & 15, q = lane >> 4;

  // staging assignment: thread -> (row tr, 16 consecutive k at tc)
  const int tr = tid >> 1;
  const int tc = (tid & 1) * 16;
  const float* ap = A + (size_t)(Mbase + tr) * 1024 + tc;
  const float* bp = W + (size_t)(Nbase + tr) * 2048 + 1024 + tc;
  short* asw = &As[tr * LDT + tc];
  short* bsw = &Bs[tr * LDT + tc];

  floatx4 acc[4][4];
  #pragma unroll
  for (int mt = 0; mt < 4; ++mt)
    #pragma unroll
    for (int nt = 0; nt < 4; ++nt) {
      floatx4 z = {0.f, 0.f, 0.f, 0.f};
      acc[mt][nt] = z;
    }

  for (int k0 = 0; k0 < 1024; k0 += 32) {
    float4 a0 = *(const float4*)(ap + k0);
    float4 a1 = *(const float4*)(ap + k0 + 4);
    float4 a2 = *(const float4*)(ap + k0 + 8);
    float4 a3 = *(const float4*)(ap + k0 + 12);
    float4 b0 = *(const float4*)(bp + k0);
    float4 b1 = *(const float4*)(bp + k0 + 4);
    float4 b2 = *(const float4*)(bp + k0 + 8);
    float4 b3 = *(const float4*)(bp + k0 + 12);
    __syncthreads();   // previous iteration's LDS reads done
    short8 pa0 = {f2b(a0.x), f2b(a0.y), f2b(a0.z), f2b(a0.w),
                  f2b(a1.x), f2b(a1.y), f2b(a1.z), f2b(a1.w)};
    short8 pa1 = {f2b(a2.x), f2b(a2.y), f2b(a2.z), f2b(a2.w),
                  f2b(a3.x), f2b(a3.y), f2b(a3.z), f2b(a3.w)};
    short8 pb0 = {f2b(b0.x), f2b(b0.y), f2b(b0.z), f2b(b0.w),
                  f2b(b1.x), f2b(b1.y), f2b(b1.z), f2b(b1.w)};
    short8 pb1 = {f2b(b2.x), f2b(b2.y), f2b(b2.z), f2b(b2.w),
                  f2b(b3.x), f2b(b3.y), f2b(b3.z), f2b(b3.w)};
    *(short8*)asw = pa0;
    *(short8*)(asw + 8) = pa1;
    *(short8*)bsw = pb0;
    *(short8*)(bsw + 8) = pb1;
    __syncthreads();

    short8 af[4], bf[4];
    #pragma unroll
    for (int mt = 0; mt < 4; ++mt)
      af[mt] = *(const short8*)&As[(wm * 64 + mt * 16 + c) * LDT + q * 8];
    #pragma unroll
    for (int nt = 0; nt < 4; ++nt)
      bf[nt] = *(const short8*)&Bs[(wn * 64 + nt * 16 + c) * LDT + q * 8];
    #pragma unroll
    for (int mt = 0; mt < 4; ++mt)
      #pragma unroll
      for (int nt = 0; nt < 4; ++nt)
        acc[mt][nt] = __builtin_amdgcn_mfma_f32_16x16x32_bf16(
            af[mt], bf[nt], acc[mt][nt], 0, 0, 0);
  }

  // Epilogue: energy = tanh(pre_e + t[b][n]); partial score = sum_n energy*v[n]
  // C layout (16x16): col = lane&15, row = (lane>>4)*4 + i  [m89-verified]
  const int mwave = Mbase + wm * 64;
  const int nwave = Nbase + wn * 64;
  float vv[4];
  #pragma unroll
  for (int nt = 0; nt < 4; ++nt) vv[nt] = vvec[nwave + nt * 16 + c];
  #pragma unroll
  for (int mt = 0; mt < 4; ++mt) {
    #pragma unroll
    for (int i = 0; i < 4; ++i) {
      const int mrow = mwave + mt * 16 + q * 4 + i;
      const float* tb = tpre + (mrow & 31) * 1024;   // b = m % 32
      float ssum = 0.f;
      #pragma unroll
      for (int nt = 0; nt < 4; ++nt) {
        float pre = acc[mt][nt][i] + tb[nwave + nt * 16 + c];
        ssum += fast_tanh(pre) * vv[nt];
      }
      #pragma unroll
      for (int off = 1; off < 16; off <<= 1) ssum += __shfl_xor(ssum, off, 64);
      if (c == 0) atomicAdd(&scores[mrow], ssum);
    }
  }
}

// softmax over s for each b: scores[s*32+b] -> out[b*2048+s]
__global__ __launch_bounds__(256) void k_softmax(
    const float* __restrict__ scores, float* __restrict__ out) {
  const int b = blockIdx.x;
  const int t = threadIdx.x;
  const int w = t >> 6, lane = t & 63;
  __shared__ float red[4];
  float vals[8];
  float m = -3.0e38f;
  #pragma unroll
  for (int i = 0; i < 8; ++i) {
    vals[i] = scores[(t + 256 * i) * 32 + b];
    m = fmaxf(m, vals[i]);
  }
  #pragma unroll
  for (int off = 32; off; off >>= 1) m = fmaxf(m, __shfl_xor(m, off, 64));
  if (lane == 0) red[w] = m;
  __syncthreads();
  m = fmaxf(fmaxf(red[0], red[1]), fmaxf(red[2], red[3]));
  __syncthreads();
  float e[8];
  float sum = 0.f;
  #pragma unroll
  for (int i = 0; i < 8; ++i) { e[i] = __expf(vals[i] - m); sum += e[i]; }
  #pragma unroll
  for (int off = 32; off; off >>= 1) sum += __shfl_xor(sum, off, 64);
  if (lane == 0) red[w] = sum;
  __syncthreads();
  sum = red[0] + red[1] + red[2] + red[3];
  const float inv = 1.0f / sum;
  #pragma unroll
  for (int i = 0; i < 8; ++i) out[b * 2048 + t + 256 * i] = e[i] * inv;
}

extern "C" void kernel_launch(void* const* d_in, const int* in_sizes, int n_in,
                              void* d_out, int out_size, void* d_ws, size_t ws_size,
                              hipStream_t stream) {
  const float* hidden = (const float*)d_in[0];   // (1,32,1024)
  const float* enc    = (const float*)d_in[1];   // (2048,32,1024)
  const float* W      = (const float*)d_in[2];   // (1024,2048)
  const float* bias   = (const float*)d_in[3];   // (1024,)
  const float* vvec   = (const float*)d_in[4];   // (1024,)
  float* out = (float*)d_out;                    // (32,1,2048) fp32

  float* scores = (float*)d_ws;                  // 65536 fp32
  float* tpre   = scores + 65536;                // 32768 fp32

  hipMemsetAsync(scores, 0, 65536 * sizeof(float), stream);
  hipLaunchKernelGGL(k_preh, dim3(8192), dim3(256), 0, stream, hidden, W, bias, tpre);
  hipLaunchKernelGGL(k_gemm, dim3(4096), dim3(256), 0, stream, enc, W, tpre, vvec, scores);
  hipLaunchKernelGGL(k_softmax, dim3(32), dim3(256), 0, stream, scores, out);
}